// Round 4
// baseline (783.072 us; speedup 1.0000x reference)
//
#include <hip/hip_runtime.h>
#include <math.h>

// Problem constants (reference: N_CENTER=4000, N_NEIGH=16, N_FEAT=64)
#define NNEI   16
#define NFEAT  64
#define NPAIR  240              // 16*15 off-diagonal pairs
#define ROWW   195              // 1 + 1 + 1 + 64 + 64 + 64
#define PER_C  (NPAIR * ROWW)   // 46800 floats per center
#define IMG    1360             // per-center unique values (words)
#define IMG4   (IMG / 4)        // 340 quads
#define COS_EPS 1e-8f

typedef float f32x4 __attribute__((ext_vector_type(4)));

// LDS value layout (flat word indices, PRE-swizzle):
//   [0   .. 255 ]  ang[j*16+k]
//   [256 .. 271 ]  d[n]
//   [272 .. 335 ]  emb_i[f]
//   [336 .. 1359]  embd[n*64+f] = emb(neighbor n)[f] / d[n]
//
// Bank swizzle: XOR low two word bits with bits [6:5]. Stays within each
// aligned 4-word quad (only low 2 bits change) -> quad-granular copies are
// swizzle-agnostic; the image is stored to global with the SAME in-quad
// permutation so expand can copy quads verbatim.
__device__ __forceinline__ int swz(int w) { return w ^ ((w >> 5) & 3); }

// flat (pair p, slot s) -> swizzled LDS word offset. Pure VALU.
__device__ __forceinline__ int off_of(int p, int s) {
    const unsigned ju = (unsigned)p / 15u;      // magic-mul
    const int j = (int)ju;
    const int r = p - (int)ju * 15;
    const int k = r + (r >= j);
    int off;
    if      (s >= 131) off = 336 + (k << 6) + (s - 131);   // emb_k / d_ik
    else if (s >= 67)  off = 336 + (j << 6) + (s - 67);    // emb_j / d_ij
    else if (s >= 3)   off = 269 + s;                      // emb_i
    else if (s == 2)   off = (j << 4) + k;                 // ang
    else if (s == 1)   off = 256 + k;                      // d_ik
    else               off = 256 + j;                      // d_ij
    return swz(off);
}

// ---- shared prologue: build the 1360-float image for center c into s_lds ----
__device__ __forceinline__ void build_image(
    int c, int tid,
    const int*   __restrict__ atom_i_idx,
    const int*   __restrict__ atom_j_idx,
    const float* __restrict__ dist_ij,
    const float* __restrict__ atoms_xyz,
    const int*   __restrict__ atoms_long,
    const float* __restrict__ embed_table,
    float* __restrict__ s_lds,
    float (* __restrict__ s_vec)[3], float* __restrict__ s_nrm,
    float* __restrict__ s_invd, int* __restrict__ s_spec)
{
    const int ii = atom_i_idx[c];           // wave-uniform

    const float xi = atoms_xyz[ii * 3 + 0];
    const float yi = atoms_xyz[ii * 3 + 1];
    const float zi = atoms_xyz[ii * 3 + 2];

    if (tid < NNEI) {
        const int jn = atom_j_idx[c * NNEI + tid];
        const float vx = atoms_xyz[jn * 3 + 0] - xi;
        const float vy = atoms_xyz[jn * 3 + 1] - yi;
        const float vz = atoms_xyz[jn * 3 + 2] - zi;
        s_vec[tid][0] = vx; s_vec[tid][1] = vy; s_vec[tid][2] = vz;
        s_nrm[tid]  = sqrtf(vx * vx + vy * vy + vz * vz);
        const float d = dist_ij[c * NNEI + tid];
        s_lds[swz(256 + tid)] = d;
        s_invd[tid] = 1.0f / d;
        s_spec[tid] = atoms_long[jn * 2 + 1];
    } else if (tid >= 64 && tid < 128) {
        const int f = tid - 64;
        const int speci = atoms_long[ii * 2 + 1];     // uniform
        s_lds[swz(272 + f)] = embed_table[speci * NFEAT + f];
    }
    __syncthreads();

    // Angle for every (j,k) in 16x16 (diagonal computed but never read).
    {
        const int j = tid >> 4, k = tid & 15;
        const float dot = s_vec[j][0] * s_vec[k][0]
                        + s_vec[j][1] * s_vec[k][1]
                        + s_vec[j][2] * s_vec[k][2];
        const float nj = fmaxf(s_nrm[j], COS_EPS);
        const float nk = fmaxf(s_nrm[k], COS_EPS);
        const float cosv = dot / (nj * nk);
        s_lds[swz(tid)] = acosf(cosv * 0.9999f);
    }
    // embd[n][f] = embed_table[spec[n]][f] / d[n]
    for (int e = tid; e < NNEI * NFEAT; e += 256) {
        const int n = e >> 6, f = e & 63;
        s_lds[swz(336 + e)] = embed_table[s_spec[n] * NFEAT + f] * s_invd[n];
    }
    __syncthreads();
}

// ---- streaming expander body: s_lds image -> 240x195 row block ----
__device__ __forceinline__ void expand_from_lds(
    int c, int tid, const float* __restrict__ s_lds, float* __restrict__ out1)
{
    f32x4* __restrict__ dst4 = (f32x4*)(out1 + (size_t)c * PER_C);
    int p = (tid << 2) / 195;
    int s = (tid << 2) - p * 195;
    #pragma unroll 2
    for (int q = tid; q < PER_C / 4; q += 256) {
        f32x4 v;
        #pragma unroll
        for (int i = 0; i < 4; ++i) {
            int pp = p, ss = s + i;
            if (ss >= 195) { pp += 1; ss -= 195; }
            v[i] = s_lds[off_of(pp, ss)];
        }
        __builtin_nontemporal_store(v, dst4 + q);
        s += 49; p += 5;              // advance by 1024 words = 5*195 + 49
        if (s >= 195) { s -= 195; p += 1; }
    }
}

// ================= Phase 1: compute images (all irregularity lives here) ====
__global__ __launch_bounds__(256) void img_build(
    const int*   __restrict__ atom_i_idx,
    const int*   __restrict__ atom_j_idx,
    const float* __restrict__ dist_ij,
    const float* __restrict__ atoms_xyz,
    const int*   __restrict__ atoms_long,
    const float* __restrict__ embed_table,
    float*       __restrict__ img,    // (C, 1360) workspace
    float*       __restrict__ out0)   // (C,)
{
    alignas(16) __shared__ float s_lds[IMG];
    __shared__ float s_vec[NNEI][3];
    __shared__ float s_nrm[NNEI];
    __shared__ float s_invd[NNEI];
    __shared__ int   s_spec[NNEI];

    const int c   = blockIdx.x;
    const int tid = threadIdx.x;
    if (tid == 0) out0[c] = (float)atom_i_idx[c];

    build_image(c, tid, atom_i_idx, atom_j_idx, dist_ij, atoms_xyz,
                atoms_long, embed_table, s_lds, s_vec, s_nrm, s_invd, s_spec);

    // Coalesced quad copy-out (plain stores: we WANT this L2/L3 resident).
    f32x4* __restrict__ dst = (f32x4*)(img + (size_t)c * IMG);
    const f32x4* __restrict__ src = (const f32x4*)s_lds;
    for (int t = tid; t < IMG4; t += 256) dst[t] = src[t];
}

// ================= Phase 2: pure streaming expander ========================
__global__ __launch_bounds__(256) void img_expand(
    const float* __restrict__ img,    // (C, 1360), in-quad pre-swizzled
    float*       __restrict__ out1)   // (C, 240, 195)
{
    alignas(16) __shared__ float s_lds[IMG];
    const int c   = blockIdx.x;
    const int tid = threadIdx.x;

    const f32x4* __restrict__ src = (const f32x4*)(img + (size_t)c * IMG);
    f32x4* __restrict__ s4 = (f32x4*)s_lds;
    for (int t = tid; t < IMG4; t += 256) s4[t] = src[t];
    __syncthreads();

    expand_from_lds(c, tid, s_lds, out1);
}

// ================= Fallback: proven fused kernel (R3) ======================
__global__ __launch_bounds__(256) void angdesc_fused(
    const int*   __restrict__ atom_i_idx,
    const int*   __restrict__ atom_j_idx,
    const float* __restrict__ dist_ij,
    const float* __restrict__ atoms_xyz,
    const int*   __restrict__ atoms_long,
    const float* __restrict__ embed_table,
    float*       __restrict__ out0,
    float*       __restrict__ out1)
{
    alignas(16) __shared__ float s_lds[IMG];
    __shared__ float s_vec[NNEI][3];
    __shared__ float s_nrm[NNEI];
    __shared__ float s_invd[NNEI];
    __shared__ int   s_spec[NNEI];

    const int c   = blockIdx.x;
    const int tid = threadIdx.x;
    if (tid == 0) out0[c] = (float)atom_i_idx[c];

    build_image(c, tid, atom_i_idx, atom_j_idx, dist_ij, atoms_xyz,
                atoms_long, embed_table, s_lds, s_vec, s_nrm, s_invd, s_spec);
    expand_from_lds(c, tid, s_lds, out1);
}

extern "C" void kernel_launch(void* const* d_in, const int* in_sizes, int n_in,
                              void* d_out, int out_size, void* d_ws, size_t ws_size,
                              hipStream_t stream) {
    // setup_inputs order: [0]=nNeigh, [1]=atom_i_idx, [2]=atom_j_idx,
    // [3]=dist_ij, [4]=atoms_xyz, [5]=atoms_long, [6]=embed_table
    const int*   atom_i_idx  = (const int*)  d_in[1];
    const int*   atom_j_idx  = (const int*)  d_in[2];
    const float* dist_ij     = (const float*)d_in[3];
    const float* atoms_xyz   = (const float*)d_in[4];
    const int*   atoms_long  = (const int*)  d_in[5];
    const float* embed_table = (const float*)d_in[6];

    const int C = in_sizes[1];              // 4000 centers
    float* out  = (float*)d_out;

    const size_t need = (size_t)C * IMG * sizeof(float);   // 21.76 MB
    if (ws_size >= need && d_ws != nullptr) {
        float* img = (float*)d_ws;
        img_build<<<C, 256, 0, stream>>>(atom_i_idx, atom_j_idx, dist_ij,
                                         atoms_xyz, atoms_long, embed_table,
                                         img, out);
        img_expand<<<C, 256, 0, stream>>>(img, out + C);
    } else {
        angdesc_fused<<<C, 256, 0, stream>>>(atom_i_idx, atom_j_idx, dist_ij,
                                             atoms_xyz, atoms_long, embed_table,
                                             out, out + C);
    }
}

// Round 5
// 765.062 us; speedup vs baseline: 1.0235x; 1.0235x over previous
//
#include <hip/hip_runtime.h>
#include <math.h>

// Problem constants (reference: N_CENTER=4000, N_NEIGH=16, N_FEAT=64)
#define NNEI   16
#define NFEAT  64
#define NPAIR  240              // 16*15 off-diagonal pairs
#define ROWW   195              // 1 + 1 + 1 + 64 + 64 + 64
#define PER_C  (NPAIR * ROWW)   // 46800 floats per center
#define IMG    1360
#define COS_EPS 1e-8f

// LDS value layout (flat word indices, PRE-swizzle):
//   [0   .. 255 ]  ang[j*16+k]
//   [256 .. 271 ]  d[n]
//   [272 .. 335 ]  emb_i[f]
//   [336 .. 1359]  embd[n*64+f] = emb(neighbor n)[f] / d[n]
__device__ __forceinline__ int swz(int w) { return w ^ ((w >> 5) & 3); }

__global__ __launch_bounds__(256) void angdesc_kernel(
    const int*   __restrict__ atom_i_idx,
    const int*   __restrict__ atom_j_idx,
    const float* __restrict__ dist_ij,
    const float* __restrict__ atoms_xyz,
    const int*   __restrict__ atoms_long,
    const float* __restrict__ embed_table,
    float*       __restrict__ out0,   // (C,)
    float*       __restrict__ out1)   // (C,240,195)
{
    __shared__ float s_lds[IMG];
    __shared__ float s_vec[NNEI][3];
    __shared__ float s_nrm[NNEI];
    __shared__ float s_invd[NNEI];
    __shared__ int   s_spec[NNEI];

    const int c   = blockIdx.x;
    const int tid = threadIdx.x;
    const int ii  = atom_i_idx[c];          // wave-uniform

    if (tid == 0) out0[c] = (float)ii;

    const float xi = atoms_xyz[ii * 3 + 0];
    const float yi = atoms_xyz[ii * 3 + 1];
    const float zi = atoms_xyz[ii * 3 + 2];

    if (tid < NNEI) {
        const int jn = atom_j_idx[c * NNEI + tid];
        const float vx = atoms_xyz[jn * 3 + 0] - xi;
        const float vy = atoms_xyz[jn * 3 + 1] - yi;
        const float vz = atoms_xyz[jn * 3 + 2] - zi;
        s_vec[tid][0] = vx; s_vec[tid][1] = vy; s_vec[tid][2] = vz;
        s_nrm[tid]  = sqrtf(vx * vx + vy * vy + vz * vz);
        const float d = dist_ij[c * NNEI + tid];
        s_lds[swz(256 + tid)] = d;
        s_invd[tid] = 1.0f / d;
        s_spec[tid] = atoms_long[jn * 2 + 1];
    } else if (tid >= 64 && tid < 128) {
        const int f = tid - 64;
        const int speci = atoms_long[ii * 2 + 1];     // uniform
        s_lds[swz(272 + f)] = embed_table[speci * NFEAT + f];
    }
    __syncthreads();

    {   // ang[j][k] for all 256 pairs (diagonal never read)
        const int j = tid >> 4, k = tid & 15;
        const float dot = s_vec[j][0] * s_vec[k][0]
                        + s_vec[j][1] * s_vec[k][1]
                        + s_vec[j][2] * s_vec[k][2];
        const float nj = fmaxf(s_nrm[j], COS_EPS);
        const float nk = fmaxf(s_nrm[k], COS_EPS);
        s_lds[swz(tid)] = acosf((dot / (nj * nk)) * 0.9999f);
    }
    for (int e = tid; e < NNEI * NFEAT; e += 256) {      // embd[n][f]
        const int n = e >> 6, f = e & 63;
        s_lds[swz(336 + e)] = embed_table[s_spec[n] * NFEAT + f] * s_invd[n];
    }
    __syncthreads();

    // ---------------- fill-like row expander ----------------
    // Row (j,k) = [d_ij, d_ik, ang, emb_i[0:64], embd_j[0:64], embd_k[0:64]].
    // Lane l, with sh=(l-3)&63, holds via ONE ds_read per segment:
    //   R[lanes 3..63] = X[l-3] (segment body), R[lanes 0..2] = X[61+l]
    //   (previous segment's tail). Then:
    //   word l      = l<3 ? scalar(l) : Ri        (v1: rotates per row)
    //   word l+64   = l<3 ? Ri        : Rj        (v2: CONSTANT for 15 rows)
    //   word l+128  = l<3 ? Rj        : Rk        (v3: rotates per row)
    //   word l+192  (l<3 only)        = Rk
    // v2 is stored 15x from the same never-rewritten register (zero vmcnt
    // waits, fill-style); v1/v3 rotate across the unrolled k-loop giving
    // ~32 independent outstanding stores per wave instead of unroll-depth 2.
    const int l  = tid & 63;          // lane
    const int w  = tid >> 6;          // wave 0..3
    const int sh = (l - 3) & 63;
    const bool head = (l < 3);

    const float Ri = s_lds[swz(272 + sh)];                  // per center

    for (int jj = 0; jj < 4; ++jj) {
        const int j = (jj << 2) | w;                        // wave-uniform
        const float Rj = s_lds[swz(336 + (j << 6) + sh)];
        const float v2 = head ? Ri : Rj;

        #pragma unroll
        for (int k = 0; k < 16; ++k) {
            if (k == j) continue;                           // uniform branch
            const float Rk = s_lds[swz(336 + (k << 6) + sh)];
            // scalars: lane0=d[j], lane1=d[k], lane2=ang[j*16+k]; lanes>=3
            // read d[j] too (uniform address -> broadcast, no conflict)
            const int sa = (l == 1) ? swz(256 + k)
                         : (l == 2) ? swz((j << 4) + k)
                                    : swz(256 + j);
            const float sc = s_lds[sa];
            const float v1 = head ? sc : Ri;
            const float v3 = head ? Rj : Rk;

            const int p = j * 15 + k - (k > j);             // row index
            float* __restrict__ rp = out1 + (size_t)c * PER_C + (size_t)p * ROWW;
            rp[l]        = v1;
            rp[l + 64]   = v2;
            rp[l + 128]  = v3;
            if (head) rp[l + 192] = Rk;
        }
    }
}

extern "C" void kernel_launch(void* const* d_in, const int* in_sizes, int n_in,
                              void* d_out, int out_size, void* d_ws, size_t ws_size,
                              hipStream_t stream) {
    // setup_inputs order: [0]=nNeigh, [1]=atom_i_idx, [2]=atom_j_idx,
    // [3]=dist_ij, [4]=atoms_xyz, [5]=atoms_long, [6]=embed_table
    const int*   atom_i_idx  = (const int*)  d_in[1];
    const int*   atom_j_idx  = (const int*)  d_in[2];
    const float* dist_ij     = (const float*)d_in[3];
    const float* atoms_xyz   = (const float*)d_in[4];
    const int*   atoms_long  = (const int*)  d_in[5];
    const float* embed_table = (const float*)d_in[6];

    const int C = in_sizes[1];              // 4000 centers
    float* out  = (float*)d_out;
    (void)d_ws; (void)ws_size;

    angdesc_kernel<<<C, 256, 0, stream>>>(atom_i_idx, atom_j_idx, dist_ij,
                                          atoms_xyz, atoms_long, embed_table,
                                          out, out + C);
}

// Round 6
// 758.611 us; speedup vs baseline: 1.0322x; 1.0085x over previous
//
#include <hip/hip_runtime.h>
#include <math.h>

// Problem constants (reference: N_CENTER=4000, N_NEIGH=16, N_FEAT=64)
#define NNEI   16
#define NFEAT  64
#define NPAIR  240              // 16*15 off-diagonal pairs
#define ROWW   195              // 1 + 1 + 1 + 64 + 64 + 64
#define PER_C  (NPAIR * ROWW)   // 46800 floats per center
#define IMG    1360
#define COS_EPS 1e-8f
#define CPB    8                // centers per persistent block
#define NBLK   512              // 2 blocks/CU on 256 CUs, one dispatch batch

typedef float f32x4 __attribute__((ext_vector_type(4)));

// LDS value layout (flat word indices, PRE-swizzle):
//   [0..255] ang[j*16+k] | [256..271] d[n] | [272..335] emb_i[f]
//   [336..1359] embd[n*64+f] = emb(neighbor n)[f] / d[n]
__device__ __host__ __forceinline__ int swz(int w) { return w ^ ((w >> 5) & 3); }

// flat (pair p, slot s) -> swizzled LDS word offset (host/offtable form)
__global__ __launch_bounds__(256) void build_offtable(unsigned short* __restrict__ tab) {
    const int t = blockIdx.x * 256 + threadIdx.x;
    if (t >= PER_C) return;
    const unsigned p = (unsigned)t / 195u;
    const int s = t - (int)p * 195;
    const unsigned ju = p / 15u;
    const int j = (int)ju;
    const int r = (int)(p - ju * 15u);
    const int k = r + (r >= j);
    const int off =
          (s >= 131) ? (336 + (k << 6) + (s - 131))
        : (s >= 67)  ? (336 + (j << 6) + (s - 67))
        : (s >= 3)   ? (269 + s)
        : (s == 2)   ? ((j << 4) + k)
        : (s == 1)   ? (256 + k)
                     : (256 + j);
    tab[t] = (unsigned short)swz(off);
}

// inline fallback (no workspace): same mapping in VALU
__device__ __forceinline__ int off_of(int p, int s) {
    const unsigned ju = (unsigned)p / 15u;
    const int j = (int)ju;
    const int r = p - (int)ju * 15;
    const int k = r + (r >= j);
    int off;
    if      (s >= 131) off = 336 + (k << 6) + (s - 131);
    else if (s >= 67)  off = 336 + (j << 6) + (s - 67);
    else if (s >= 3)   off = 269 + s;
    else if (s == 2)   off = (j << 4) + k;
    else if (s == 1)   off = 256 + k;
    else               off = 256 + j;
    return swz(off);
}

template <bool USE_TAB>
__global__ __launch_bounds__(256) void angdesc_persist(
    const int*   __restrict__ atom_i_idx,
    const int*   __restrict__ atom_j_idx,
    const float* __restrict__ dist_ij,
    const float* __restrict__ atoms_xyz,
    const int*   __restrict__ atoms_long,
    const float* __restrict__ embed_table,
    const unsigned short* __restrict__ tab,
    float*       __restrict__ out0,   // (C,)
    float*       __restrict__ out1,   // (C,240,195)
    int C)
{
    alignas(16) __shared__ float s_lds[IMG];
    __shared__ float s_vec[NNEI][3];
    __shared__ float s_nrm[NNEI];
    __shared__ float s_invd[NNEI];
    __shared__ int   s_spec[NNEI];

    const int tid = threadIdx.x;
    // Bijective XCD swizzle (NBLK=512 % 8 == 0): HW round-robins blockIdx
    // across the 8 XCDs; remap so each XCD owns a CONTIGUOUS 64-block =
    // 512-center = ~96 MB output span (compact per-L2 writeback stream).
    const int b = blockIdx.x;
    const int logical = ((b & 7) << 6) + (b >> 3);
    const int c0 = logical * CPB;

    for (int c = c0; c < c0 + CPB && c < C; ++c) {
        __syncthreads();              // s_lds reuse guard across centers

        // ---------------- build image for center c ----------------
        const int ii = atom_i_idx[c];            // wave-uniform
        if (tid == 0) out0[c] = (float)ii;
        const float xi = atoms_xyz[ii * 3 + 0];
        const float yi = atoms_xyz[ii * 3 + 1];
        const float zi = atoms_xyz[ii * 3 + 2];

        if (tid < NNEI) {
            const int jn = atom_j_idx[c * NNEI + tid];
            const float vx = atoms_xyz[jn * 3 + 0] - xi;
            const float vy = atoms_xyz[jn * 3 + 1] - yi;
            const float vz = atoms_xyz[jn * 3 + 2] - zi;
            s_vec[tid][0] = vx; s_vec[tid][1] = vy; s_vec[tid][2] = vz;
            s_nrm[tid]  = sqrtf(vx * vx + vy * vy + vz * vz);
            const float d = dist_ij[c * NNEI + tid];
            s_lds[swz(256 + tid)] = d;
            s_invd[tid] = 1.0f / d;
            s_spec[tid] = atoms_long[jn * 2 + 1];
        } else if (tid >= 64 && tid < 128) {
            const int f = tid - 64;
            const int speci = atoms_long[ii * 2 + 1];   // uniform
            s_lds[swz(272 + f)] = embed_table[speci * NFEAT + f];
        }
        __syncthreads();

        {   // ang[j][k] for all 256 (j,k); diagonal never read
            const int j = tid >> 4, k = tid & 15;
            const float dot = s_vec[j][0] * s_vec[k][0]
                            + s_vec[j][1] * s_vec[k][1]
                            + s_vec[j][2] * s_vec[k][2];
            const float nj = fmaxf(s_nrm[j], COS_EPS);
            const float nk = fmaxf(s_nrm[k], COS_EPS);
            s_lds[swz(tid)] = acosf((dot / (nj * nk)) * 0.9999f);
        }
        for (int e = tid; e < NNEI * NFEAT; e += 256) {
            const int n = e >> 6, f = e & 63;
            s_lds[swz(336 + e)] = embed_table[s_spec[n] * NFEAT + f] * s_invd[n];
        }
        __syncthreads();

        // ---------------- expand: 1360-word image -> 187 KB ----------------
        f32x4* __restrict__ dst4 = (f32x4*)(out1 + (size_t)c * PER_C);
        if constexpr (USE_TAB) {
            const ushort4* __restrict__ tab4 = (const ushort4*)tab;
            #pragma unroll 2
            for (int q = tid; q < PER_C / 4; q += 256) {
                const ushort4 o = tab4[q];
                f32x4 v;
                v.x = s_lds[o.x];
                v.y = s_lds[o.y];
                v.z = s_lds[o.z];
                v.w = s_lds[o.w];
                __builtin_nontemporal_store(v, dst4 + q);
            }
        } else {
            int p = (tid << 2) / 195;
            int s = (tid << 2) - p * 195;
            #pragma unroll 2
            for (int q = tid; q < PER_C / 4; q += 256) {
                f32x4 v;
                #pragma unroll
                for (int i = 0; i < 4; ++i) {
                    int pp = p, ss = s + i;
                    if (ss >= 195) { pp += 1; ss -= 195; }
                    v[i] = s_lds[off_of(pp, ss)];
                }
                __builtin_nontemporal_store(v, dst4 + q);
                s += 49; p += 5;
                if (s >= 195) { s -= 195; p += 1; }
            }
        }
    }
}

extern "C" void kernel_launch(void* const* d_in, const int* in_sizes, int n_in,
                              void* d_out, int out_size, void* d_ws, size_t ws_size,
                              hipStream_t stream) {
    // setup_inputs order: [0]=nNeigh, [1]=atom_i_idx, [2]=atom_j_idx,
    // [3]=dist_ij, [4]=atoms_xyz, [5]=atoms_long, [6]=embed_table
    const int*   atom_i_idx  = (const int*)  d_in[1];
    const int*   atom_j_idx  = (const int*)  d_in[2];
    const float* dist_ij     = (const float*)d_in[3];
    const float* atoms_xyz   = (const float*)d_in[4];
    const int*   atoms_long  = (const int*)  d_in[5];
    const float* embed_table = (const float*)d_in[6];

    const int C = in_sizes[1];              // 4000 centers
    float* out  = (float*)d_out;

    const size_t need = (size_t)PER_C * sizeof(unsigned short);   // 93.6 KB
    if (d_ws != nullptr && ws_size >= need) {
        unsigned short* tab = (unsigned short*)d_ws;
        build_offtable<<<(PER_C + 255) / 256, 256, 0, stream>>>(tab);
        angdesc_persist<true><<<NBLK, 256, 0, stream>>>(
            atom_i_idx, atom_j_idx, dist_ij, atoms_xyz, atoms_long,
            embed_table, tab, out, out + C, C);
    } else {
        angdesc_persist<false><<<NBLK, 256, 0, stream>>>(
            atom_i_idx, atom_j_idx, dist_ij, atoms_xyz, atoms_long,
            embed_table, nullptr, out, out + C, C);
    }
}